// Round 9
// baseline (213.673 us; speedup 1.0000x reference)
//
#include <hip/hip_runtime.h>
#include <hip/hip_bf16.h>
#include <math.h>

// GuidedAttention: B=4, TA=TV=1024, D=512, H=8, HD=64. All I/O fp32.
// bf16 MFMA internally, fp32 accumulate.
// Round 18 (= r17 probe resubmitted after infra failure): prep_all, gemm_qkv,
// gemm_out_ln each launched twice (idempotent, identical args). attn once.
// dur delta vs r15 (170.4) = T_prep + T_qkv + T_ln + 3 gaps. r16 gave
// T_attn+gap = 23.0. All kernel bodies byte-identical to r15.
typedef __bf16 bf16_t;
typedef _Float16 hf16_t;
typedef bf16_t bf16x8 __attribute__((ext_vector_type(8)));
typedef bf16_t bf16x4 __attribute__((ext_vector_type(4)));
typedef hf16_t hf16x8 __attribute__((ext_vector_type(8)));
typedef float f32x4 __attribute__((ext_vector_type(4)));
typedef short s16x4 __attribute__((ext_vector_type(4)));

#define B_  4
#define TA_ 1024
#define TV_ 1024
#define D_  512
#define H_  8
#define HD_ 64
#define SCALE_ 0.125f
#define LOG2E_ 1.442695041f
// SCALE * log2(e): folded into Q so attn logits are in log2 units.
#define QSCALE_ 0.1803368801f
// defer-max threshold: 8 nats in log2 units
#define DEFER_THR_ 11.5416f

// hardware exp2 (v_exp_f32). __exp2f is taken by a glibc math.h macro.
__device__ inline float fast_exp2(float x) { return __builtin_amdgcn_exp2f(x); }

// async global->LDS copy, 16 B per lane (global_load_lds_dwordx4).
__device__ inline void g2l16(const void* g, void* l) {
    __builtin_amdgcn_global_load_lds(
        (const __attribute__((address_space(1))) void*)g,
        (__attribute__((address_space(3))) void*)l, 16, 0, 0);
}

__device__ inline f32x4 mfma16_bf16(bf16x4 a, bf16x4 b, f32x4 c) {
    return __builtin_amdgcn_mfma_f32_16x16x16bf16_1k(
        __builtin_bit_cast(s16x4, a), __builtin_bit_cast(s16x4, b), c, 0, 0, 0);
}

// ---- fused prep: blocks [0,1024) = bias tiling; [1024, 4608) = fp32->bf16 cvt.
// bias_t[b][kt][q64][tid][ct*4+r] = log(G[b][q64*64+wave*16+l16][kt*64+ct*16+quad*4+r]+1e-8)
// (S^T fragment order: q = l16, k = 16ct+4quad+r)
__global__ __launch_bounds__(256) void prep_all(
    const float* __restrict__ G, hf16_t* __restrict__ bias_t,
    const float* __restrict__ q, const float* __restrict__ k, const float* __restrict__ v,
    const float* __restrict__ Wq, const float* __restrict__ Wk,
    const float* __restrict__ Wv, const float* __restrict__ Wo,
    bf16_t* __restrict__ qb, bf16_t* __restrict__ kb, bf16_t* __restrict__ vb,
    bf16_t* __restrict__ Wb)
{
    const int tid = threadIdx.x;
    if (blockIdx.x < 1024) {
        __shared__ float Gt[64][68];
        const int kt = blockIdx.x & 15, q64 = (blockIdx.x >> 4) & 15, b = blockIdx.x >> 8;
        const int row = tid >> 4, col4 = (tid & 15) * 4;
        #pragma unroll
        for (int it = 0; it < 4; ++it) {
            int r = it * 16 + row;
            f32x4 g = *(const f32x4*)(G + ((size_t)(b * TA_ + q64 * 64 + r)) * TV_ + kt * 64 + col4);
            *(f32x4*)&Gt[r][col4] = g;
        }
        __syncthreads();
        const int lane = tid & 63, wave = tid >> 6, quad = lane >> 4, l16 = lane & 15;
        hf16x8 lo, hi;
        #pragma unroll
        for (int ct = 0; ct < 4; ++ct) {
            #pragma unroll
            for (int r = 0; r < 4; ++r) {
                float gv = Gt[wave * 16 + l16][ct * 16 + quad * 4 + r];
                float lb = __logf(gv + 1e-8f);
                int idx = ct * 4 + r;
                if (idx < 8) lo[idx] = (hf16_t)lb; else hi[idx - 8] = (hf16_t)lb;
            }
        }
        size_t doff = ((((size_t)b * 16 + kt) * 16 + q64) * 256 + tid) * 16;
        *(hf16x8*)(bias_t + doff) = lo;
        *(hf16x8*)(bias_t + doff + 8) = hi;
    } else {
        const size_t i = ((size_t)(blockIdx.x - 1024) * 256 + tid) * 8;
        const float* src; bf16_t* dst; size_t off;
        const size_t M2 = (size_t)1 << 21;
        if (i < M2)          { src = q; dst = qb; off = i; }
        else if (i < 2 * M2) { src = k; dst = kb; off = i - M2; }
        else if (i < 3 * M2) { src = v; dst = vb; off = i - 2 * M2; }
        else {
            size_t j = i - 3 * M2;
            int wsel = (int)(j >> 18); off = j & 262143;
            src = (wsel == 0) ? Wq : (wsel == 1) ? Wk : (wsel == 2) ? Wv : Wo;
            dst = Wb + ((size_t)wsel << 18);
        }
        f32x4 a = *(const f32x4*)(src + off), c = *(const f32x4*)(src + off + 4);
        bf16x8 r;
        #pragma unroll
        for (int t = 0; t < 4; ++t) { r[t] = (bf16_t)a[t]; r[t + 4] = (bf16_t)c[t]; }
        *(bf16x8*)(dst + off) = r;
    }
}

// Fused QKV projection, 128x64 tiles (3 blocks/CU). z=0: qb->Qp [B,H,T,HD]
// (pre-scaled by SCALE*log2e); z=1: kb->Kp; z=2: vb->Vt [B,H,HD,T] (bf16x4 stores)
__global__ __launch_bounds__(256) void gemm_qkv(
    const bf16_t* __restrict__ qb, const bf16_t* __restrict__ kb, const bf16_t* __restrict__ vb,
    const bf16_t* __restrict__ Wb,
    const float* __restrict__ bq, const float* __restrict__ bk, const float* __restrict__ bv,
    bf16_t* __restrict__ Qp, bf16_t* __restrict__ Kp, bf16_t* __restrict__ Vt)
{
    __shared__ bf16_t Asm[2][128 * 32];   // 8 KB per buf
    __shared__ bf16_t Bsm[2][64 * 32];    // 4 KB per buf

    const int tid  = threadIdx.x;
    const int wave = tid >> 6, lane = tid & 63;
    const int quad = lane >> 4, l16 = lane & 15;
    const int wm = wave & 1, wn = wave >> 1;      // wm: 2x64 rows, wn: 2x32 cols
    const int mbase = blockIdx.x * 128, nbase = blockIdx.y * 64;
    const int z = blockIdx.z;
    const int srow = lane >> 2;           // staging: 16 rows x 4 chunks of 16B
    const int scol = (lane & 3) * 8;      // elements

    const bf16_t* X   = (z == 0) ? qb : (z == 1) ? kb : vb;
    const float* bias = (z == 0) ? bq : (z == 1) ? bk : bv;
    const bf16_t* W   = Wb + ((size_t)z << 18);

    auto stage = [&](int kt, int buf) {
        const int k0 = kt * 32;
        #pragma unroll
        for (int i = 0; i < 2; ++i) {          // A rows: wave*32 .. +32
            const int row = wave * 32 + i * 16;
            g2l16(X + (size_t)(mbase + row + srow) * D_ + k0 + scol,
                  &Asm[buf][row * 32] + (size_t)lane * 8);
        }
        {                                       // B rows: wave*16 .. +16
            const int row = wave * 16;
            g2l16(W + (size_t)(nbase + row + srow) * D_ + k0 + scol,
                  &Bsm[buf][row * 32] + (size_t)lane * 8);
        }
    };

    f32x4 acc[4][2] = {};
    stage(0, 0);
    __syncthreads();
    for (int kt = 0; kt < 16; ++kt) {
        const int buf = kt & 1;
        if (kt < 15) stage(kt + 1, buf ^ 1);
        bf16x8 af[4], bf_[2];
        #pragma unroll
        for (int t = 0; t < 4; ++t)
            af[t]  = *(const bf16x8*)&Asm[buf][(wm * 64 + t * 16 + l16) * 32 + quad * 8];
        #pragma unroll
        for (int t = 0; t < 2; ++t)
            bf_[t] = *(const bf16x8*)&Bsm[buf][(wn * 32 + t * 16 + l16) * 32 + quad * 8];
        #pragma unroll
        for (int mt = 0; mt < 4; ++mt) {
            #pragma unroll
            for (int nt = 0; nt < 2; ++nt)
                acc[mt][nt] = __builtin_amdgcn_mfma_f32_16x16x32_bf16(af[mt], bf_[nt], acc[mt][nt], 0, 0, 0);
        }
        __syncthreads();
    }

    bf16_t* out = (z == 0) ? Qp : (z == 1) ? Kp : Vt;
    #pragma unroll
    for (int mt = 0; mt < 4; ++mt) {
        #pragma unroll
        for (int nt = 0; nt < 2; ++nt) {
            const int n = nbase + wn * 32 + nt * 16 + l16;
            const float bn = bias[n];
            if (z == 2) {
                // 4 consecutive t for r=0..3 -> one aligned 8B store
                int m0 = mbase + wm * 64 + mt * 16 + quad * 4;
                int b = m0 >> 10, t = m0 & 1023, h = n >> 6, hd = n & 63;
                bf16x4 pk;
                #pragma unroll
                for (int r = 0; r < 4; ++r) pk[r] = (bf16_t)(acc[mt][nt][r] + bn);
                *(bf16x4*)(out + ((size_t)(b * H_ + h) * HD_ + hd) * TV_ + t) = pk;
            } else {
                #pragma unroll
                for (int r = 0; r < 4; ++r) {
                    int m = mbase + wm * 64 + mt * 16 + quad * 4 + r;  // token index
                    float val = acc[mt][nt][r] + bn;
                    if (z == 0) val *= QSCALE_;
                    int b = m >> 10, t = m & 1023, h = n >> 6, hd = n & 63;
                    out[(((size_t)(b * H_ + h) * TA_) + t) * HD_ + hd] = (bf16_t)val;
                }
            }
        }
    }
}

// ---- Flash attention, in-block split-K, S^T formulation. 512 threads.
// Waves 0-3: k-tiles 0-7; waves 4-7: k-tiles 8-15 (independent K/V LDS halves).
// S^T frag: q=l16, k=16ct+4quad+r -> per-lane softmax + register P -> 16x16x16 PV.
// Ksm: 16B-granule XOR swizzle (g ^= row&7) on write + both reads.
// Vsm: stride 76 (bank stride 6 mod 32 -> conflict-free-ish); 2x bf16x4 writes.
// Final: half-1 dumps fp32 O/m/l into dead Ksm space; half-0 merges, writes ctx.
__global__ __launch_bounds__(512, 4) void attn_kernel(
    const bf16_t* __restrict__ Qp, const bf16_t* __restrict__ Kp,
    const bf16_t* __restrict__ Vt, const hf16_t* __restrict__ bias_t,
    const float* __restrict__ bias_scale, bf16_t* __restrict__ ctx)
{
    __shared__ bf16_t Ksm[2][2][64][72];   // [half][buf][krow][hd], XOR-swizzled
    __shared__ bf16_t Vsm[2][2][64][76];   // [half][buf][hd][kcol], stride 76

    const int tid  = threadIdx.x;
    const int wave = tid >> 6, lane = tid & 63;
    const int half = wave >> 2, w4 = wave & 3;
    const int quad = lane >> 4, l16 = lane & 15;
    const int bh = blockIdx.x, b = bh >> 3, h = bh & 7;
    const int q64 = blockIdx.y;
    const int t0 = half * 8;            // first k-tile for this half
    const int qbase = q64 * 64 + w4 * 16;
    const int rsub = lane >> 3, csub = lane & 7;   // staging: 8 rows x 8 chunks of 16B
    // shuffle source lane: same quad, l16' = quad*4+r  (|r at use site)
    const int shsrc = (lane & 48) | ((lane >> 2) & 12);

    // softplus(bias_scale) * log2e (logits kept in log2 units)
    const float sp = log1pf(__expf(bias_scale[0])) * LOG2E_;

    // Q fragments (MFMA B operand: n=l16=q, k=hd)
    bf16x8 aq[2];
    #pragma unroll
    for (int s = 0; s < 2; ++s)
        aq[s] = *(const bf16x8*)(Qp + ((size_t)bh * TA_ + qbase + l16) * HD_ + s * 32 + quad * 8);

    f32x4 o[4] = {};
    float m_ = -1e30f, l_ = 0.f;   // per-lane: q-row l16 (log2 units)

    auto issue_kv = [&](int kt, bf16x8 kr[2], bf16x8 vr[2]) {
        const int kbase = kt * 64;
        #pragma unroll
        for (int i = 0; i < 2; ++i) {
            int row = w4 * 16 + i * 8 + rsub;
            kr[i] = *(const bf16x8*)(Kp + ((size_t)bh * TV_ + kbase + row) * HD_ + csub * 8);
            vr[i] = *(const bf16x8*)(Vt + ((size_t)bh * HD_ + row) * TV_ + kbase + csub * 8);
        }
    };
    auto write_kv = [&](int buf, bf16x8 kr[2], bf16x8 vr[2]) {
        #pragma unroll
        for (int i = 0; i < 2; ++i) {
            int row = w4 * 16 + i * 8 + rsub;
            // K: swizzled 16B granule (write side of the involution)
            *(bf16x8*)&Ksm[half][buf][row][(csub ^ (row & 7)) * 8] = kr[i];
            // V: stride-76 rows; odd rows only 8B-aligned -> two bf16x4 stores
            *(bf16x4*)&Vsm[half][buf][row][csub * 8]     = *(const bf16x4*)&vr[i];
            *(bf16x4*)&Vsm[half][buf][row][csub * 8 + 4] = *((const bf16x4*)&vr[i] + 1);
        }
    };

    const int tidb = (w4 << 6) | lane;   // 0..255 packet index within (b,kt,q64)
    const hf16_t* bias_base = bias_t + (((size_t)b * 16 * 16 + q64) * 256 + tidb) * 16;
    auto bias_ld = [&](int kt, hf16x8& lo, hf16x8& hi) {
        const hf16_t* bp = bias_base + (size_t)kt * 65536;  // kt stride = 16*256*16
        lo = *(const hf16x8*)bp;
        hi = *(const hf16x8*)(bp + 8);
    };
    // static ring slots: slot0 = even local tiles, slot1 = odd
    hf16x8 b0lo, b0hi, b1lo, b1hi;
    bias_ld(t0, b0lo, b0hi);
    bias_ld(t0 + 1, b1lo, b1hi);

    {
        bf16x8 kr[2], vr[2];
        issue_kv(t0, kr, vr);
        write_kv(0, kr, vr);
    }
    __syncthreads();

    // one K-tile; lk = local tile index (0..7), buf literal, static ring slot refs
    auto tile_body = [&](int lk, int buf, hf16x8& slo, hf16x8& shi) {
        const int kt = t0 + lk;
        bf16x8 krn[2], vrn[2];
        if (lk < 7) issue_kv(kt + 1, krn, vrn);
        hf16x8 clo = slo, chi = shi;
        if (lk < 6) bias_ld(kt + 2, slo, shi);

        // S^T = K . Q^T  (A = K frag from Ksm swizzled, B = Q frag; Q pre-scaled)
        f32x4 st[4];
        __builtin_amdgcn_s_setprio(1);
        #pragma unroll
        for (int ct = 0; ct < 4; ++ct) {
            f32x4 acc = {};
            #pragma unroll
            for (int s = 0; s < 2; ++s) {
                bf16x8 bk = *(const bf16x8*)&Ksm[half][buf][ct * 16 + l16]
                                                 [((4 * s + quad) ^ (l16 & 7)) * 8];
                acc = __builtin_amdgcn_mfma_f32_16x16x32_bf16(bk, aq[s], acc, 0, 0, 0);
            }
            st[ct] = acc;
        }
        __builtin_amdgcn_s_setprio(0);
        // bias + per-lane softmax over 16 regs (k = 16ct+4quad+r for q = l16)
        float sv[4][4], mx = -1e30f;
        #pragma unroll
        for (int ct = 0; ct < 4; ++ct) {
            #pragma unroll
            for (int r = 0; r < 4; ++r) {
                int idx = ct * 4 + r;
                float lb = (idx < 8) ? (float)clo[idx] : (float)chi[idx - 8];
                float val = fmaf(lb, sp, st[ct][r]);
                sv[ct][r] = val;
                mx = fmaxf(mx, val);
            }
        }
        mx = fmaxf(mx, __shfl_xor(mx, 16, 64));
        mx = fmaxf(mx, __shfl_xor(mx, 32, 64));
        // defer-max (T13): skip O-rescale when tile max growth <= 8 nats.
        // Wave-uniform branch; exact when mx <= m_.
        float mn;
        if (__all(mx - m_ <= DEFER_THR_)) {
            mn = m_;
        } else {
            mn = fmaxf(m_, mx);
            float alpha = fast_exp2(m_ - mn);
            m_ = mn;
            l_ *= alpha;
            // redistribute alpha to O's C-frag rows (q = quad*4+r), rescale O
            #pragma unroll
            for (int r = 0; r < 4; ++r) {
                float af = __shfl(alpha, shsrc | r, 64);
                #pragma unroll
                for (int dt = 0; dt < 4; ++dt) o[dt][r] *= af;
            }
        }
        float ls = 0.f;
        #pragma unroll
        for (int ct = 0; ct < 4; ++ct) {
            #pragma unroll
            for (int r = 0; r < 4; ++r) {
                float p = fast_exp2(sv[ct][r] - mn);
                sv[ct][r] = p;
                ls += p;
            }
        }
        ls += __shfl_xor(ls, 16, 64);
        ls += __shfl_xor(ls, 32, 64);
        l_ += ls;
        // stage next tile into buf^1 now: ds_writes drain under the PV MFMAs
        if (lk < 7) write_kv(buf ^ 1, krn, vrn);
        // O += P.V via 16x16x16 MFMA: A = P chunk (regs), B = V chunk (b64 from Vsm)
        __builtin_amdgcn_s_setprio(1);
        #pragma unroll
        for (int ct = 0; ct < 4; ++ct) {
            bf16x4 ap;
            #pragma unroll
            for (int r = 0; r < 4; ++r) ap[r] = (bf16_t)sv[ct][r];
            #pragma unroll
            for (int dt = 0; dt < 4; ++dt) {
                bf16x4 bv = *(const bf16x4*)&Vsm[half][buf][dt * 16 + l16][ct * 16 + quad * 4];
                o[dt] = mfma16_bf16(ap, bv, o[dt]);
            }
        }
        __builtin_amdgcn_s_setprio(0);
        __syncthreads();
    };

    #pragma unroll 1
    for (int kk = 0; kk < 8; kk += 2) {
        tile_body(kk,     0, b0lo, b0hi);
        tile_body(kk + 1, 1, b1lo, b1hi);
    }

    // ---- in-block combine: Ksm is dead; reuse as fp32 buffer [256][18]
    float* cb = (float*)&Ksm[0][0][0][0];
    if (half == 1) {
        float* p = cb + (size_t)tidb * 18;
        #pragma unroll
        for (int dt = 0; dt < 4; ++dt) {
            #pragma unroll
            for (int r = 0; r < 4; ++r) p[dt * 4 + r] = o[dt][r];
        }
        p[16] = m_; p[17] = l_;
    }
    __syncthreads();
    if (half == 0) {
        const float* p = cb + (size_t)tidb * 18;   // half1's same-lane O
        float s0[4], s1[4];
        #pragma unroll
        for (int r = 0; r < 4; ++r) {
            float m0 = __shfl(m_, shsrc | r, 64);
            float l0 = __shfl(l_, shsrc | r, 64);
            const float* pr = cb + (size_t)((w4 << 6) | (shsrc | r)) * 18;
            float m1 = pr[16], l1 = pr[17];
            float mm = fmaxf(m0, m1);
            float e0 = fast_exp2(m0 - mm), e1 = fast_exp2(m1 - mm);
            float L = l0 * e0 + l1 * e1;
            s0[r] = e0 / L; s1[r] = e1 / L;
        }
        #pragma unroll
        for (int dt = 0; dt < 4; ++dt) {
            #pragma unroll
            for (int r = 0; r < 4; ++r) {
                float v = o[dt][r] * s0[r] + p[dt * 4 + r] * s1[r];
                int qrow = q64 * 64 + w4 * 16 + quad * 4 + r;
                ctx[((size_t)b * TA_ + qrow) * D_ + h * HD_ + dt * 16 + l16] = (bf16_t)v;
            }
        }
    }
}

// ---- Fused out-projection + gated residual + LayerNorm.
// Block: 16 tokens x full 512 cols, 512 threads, grid 256 (1 block/CU).
// Each wave owns 64 cols (4x nt) for all 16 tokens. LN row stats: shfl_xor
// over l16 lanes, then [16][8] LDS combine across the 8 waves.
__global__ __launch_bounds__(512) void gemm_out_ln(
    const bf16_t* __restrict__ ctx, const bf16_t* __restrict__ Wob,
    const float* __restrict__ bo, const float* __restrict__ q,
    const float* __restrict__ gamma, const float* __restrict__ beta,
    const float* __restrict__ gate, float* __restrict__ y)
{
    __shared__ bf16_t Asm[2][16 * 32];    // 1 KB per buf
    __shared__ bf16_t Bsm[2][512 * 32];   // 32 KB per buf
    __shared__ float ps[16][8], psq[16][8];

    const int tid  = threadIdx.x;
    const int wave = tid >> 6, lane = tid & 63;
    const int quad = lane >> 4, l16 = lane & 15;
    const int mbase = blockIdx.x * 16;

    auto stage = [&](int kt, int buf) {
        const int k0 = kt * 32;
        #pragma unroll
        for (int j = 0; j < 4; ++j) {
            int row0 = wave * 64 + j * 16;   // B rows [row0, row0+16)
            g2l16(Wob + (size_t)(row0 + (lane >> 2)) * D_ + k0 + (lane & 3) * 8,
                  &Bsm[buf][row0 * 32] + (size_t)lane * 8);
        }
        if (wave == 0) {                     // A rows [0,16)
            g2l16(ctx + (size_t)(mbase + (lane >> 2)) * D_ + k0 + (lane & 3) * 8,
                  &Asm[buf][0] + (size_t)lane * 8);
        }
    };

    f32x4 acc[4] = {};
    stage(0, 0);
    __syncthreads();
    for (int kt = 0; kt < 16; ++kt) {
        const int buf = kt & 1;
        if (kt < 15) stage(kt + 1, buf ^ 1);
        bf16x8 af = *(const bf16x8*)&Asm[buf][l16 * 32 + quad * 8];
        #pragma unroll
        for (int nt = 0; nt < 4; ++nt) {
            bf16x8 bf_ = *(const bf16x8*)&Bsm[buf][(wave * 64 + nt * 16 + l16) * 32 + quad * 8];
            acc[nt] = __builtin_amdgcn_mfma_f32_16x16x32_bf16(af, bf_, acc[nt], 0, 0, 0);
        }
        __syncthreads();
    }

    const float sg = 1.f / (1.f + __expf(-gate[0]));
    // x = q + sg*(acc + bo); keep x in acc; accumulate row partials (64 cols/wave)
    float s[4] = {0.f, 0.f, 0.f, 0.f}, sq[4] = {0.f, 0.f, 0.f, 0.f};
    #pragma unroll
    for (int nt = 0; nt < 4; ++nt) {
        int n = wave * 64 + nt * 16 + l16;
        float bon = bo[n];
        #pragma unroll
        for (int r = 0; r < 4; ++r) {
            int m = mbase + quad * 4 + r;
            float x = q[(size_t)m * D_ + n] + sg * (acc[nt][r] + bon);
            acc[nt][r] = x;
            s[r] += x; sq[r] += x * x;
        }
    }
    // reduce over the 16 l16-lanes (offsets stay inside the quad-group)
    #pragma unroll
    for (int off = 1; off < 16; off <<= 1) {
        #pragma unroll
        for (int r = 0; r < 4; ++r) {
            s[r]  += __shfl_xor(s[r],  off, 64);
            sq[r] += __shfl_xor(sq[r], off, 64);
        }
    }
    if (l16 == 0) {
        #pragma unroll
        for (int r = 0; r < 4; ++r) {
            ps[quad * 4 + r][wave]  = s[r];
            psq[quad * 4 + r][wave] = sq[r];
        }
    }
    __syncthreads();
    float mu[4], rstd[4];
    #pragma unroll
    for (int r = 0; r < 4; ++r) {
        int row = quad * 4 + r;
        float S = 0.f, SQ = 0.f;
        #pragma unroll
        for (int wv = 0; wv < 8; ++wv) { S += ps[row][wv]; SQ += psq[row][wv]; }
        mu[r] = S * (1.f / D_);
        float var = SQ * (1.f / D_) - mu[r] * mu[r];
        rstd[r] = rsqrtf(var + 1e-5f);
    }
    #pragma unroll
    for (int nt = 0; nt < 4; ++nt) {
        int n = wave * 64 + nt * 16 + l16;
        float gn = gamma[n], bn = beta[n];
        #pragma unroll
        for (int r = 0; r < 4; ++r) {
            int m = mbase + quad * 4 + r;
            y[(size_t)m * D_ + n] = (acc[nt][r] - mu[r]) * rstd[r] * gn + bn;
        }
    }
}

extern "C" void kernel_launch(void* const* d_in, const int* in_sizes, int n_in,
                              void* d_out, int out_size, void* d_ws, size_t ws_size,
                              hipStream_t stream) {
    const float* q       = (const float*)d_in[0];
    const float* k       = (const float*)d_in[1];
    const float* v       = (const float*)d_in[2];
    const float* guide   = (const float*)d_in[3];
    const float* Wq      = (const float*)d_in[4];
    const float* bq      = (const float*)d_in[5];
    const float* Wk      = (const float*)d_in[6];
    const float* bk      = (const float*)d_in[7];
    const float* Wv      = (const float*)d_in[8];
    const float* bv      = (const float*)d_in[9];
    const float* Wo      = (const float*)d_in[10];
    const float* bo      = (const float*)d_in[11];
    const float* gamma   = (const float*)d_in[12];
    const float* beta    = (const float*)d_in[13];
    const float* gate    = (const float*)d_in[14];
    const float* bscale  = (const float*)d_in[15];

    char* w = (char*)d_ws;
    bf16_t* qb     = (bf16_t*)(w);                  // 4 MB bf16 [4096,512]
    bf16_t* kb     = (bf16_t*)(w + (4u  << 20));    // 4 MB
    bf16_t* vb     = (bf16_t*)(w + (8u  << 20));    // 4 MB
    bf16_t* Wb     = (bf16_t*)(w + (12u << 20));    // 2 MB concat Wq,Wk,Wv,Wo bf16
    bf16_t* Qp     = (bf16_t*)(w + (14u << 20));    // 4 MB [B,H,TA,HD] (pre-scaled)
    bf16_t* Kp     = (bf16_t*)(w + (18u << 20));    // 4 MB [B,H,TV,HD]
    bf16_t* Vt     = (bf16_t*)(w + (22u << 20));    // 4 MB [B,H,HD,TV]
    bf16_t* ctx    = (bf16_t*)(w + (26u << 20));    // 4 MB [B,TA,D]
    hf16_t* bias_t = (hf16_t*)(w + (30u << 20));    // 8 MB tiled fp16

    // PROBE #2: prep/qkv/ln each twice (idempotent). delta vs r15 = P+Q+L+3g.
    prep_all<<<4608, 256, 0, stream>>>(guide, bias_t, q, k, v, Wq, Wk, Wv, Wo, qb, kb, vb, Wb);
    prep_all<<<4608, 256, 0, stream>>>(guide, bias_t, q, k, v, Wq, Wk, Wv, Wo, qb, kb, vb, Wb);
    gemm_qkv<<<dim3(32, 8, 3), 256, 0, stream>>>(qb, kb, vb, Wb, bq, bk, bv, Qp, Kp, Vt);
    gemm_qkv<<<dim3(32, 8, 3), 256, 0, stream>>>(qb, kb, vb, Wb, bq, bk, bv, Qp, Kp, Vt);
    attn_kernel<<<dim3(32, 16), 512, 0, stream>>>(Qp, Kp, Vt, bias_t, bscale, ctx);
    gemm_out_ln<<<256, 512, 0, stream>>>(ctx, Wb + ((size_t)3 << 18), bo, q,
                                         gamma, beta, gate, (float*)d_out);
    gemm_out_ln<<<256, 512, 0, stream>>>(ctx, Wb + ((size_t)3 << 18), bo, q,
                                         gamma, beta, gate, (float*)d_out);
}

// Round 10
// 167.652 us; speedup vs baseline: 1.2745x; 1.2745x over previous
//
#include <hip/hip_runtime.h>
#include <hip/hip_bf16.h>
#include <math.h>

// GuidedAttention: B=4, TA=TV=1024, D=512, H=8, HD=64. All I/O fp32.
// bf16 MFMA internally, fp32 accumulate.
// Round 19: probes reverted. Bias-tiling (1024 blocks, independent of qkv)
// moved INTO the gemm_qkv launch (flat grid 768 qkv + 1024 bias, smem union)
// so it overlaps qkv's MFMA phase instead of serializing before it.
// prep_all is now cvt-only (3584 blocks). attn/ln unchanged from r15.
// Decomposition (r16/r18 probes): kernels+gaps ~66us, harness-fixed ~104us.
typedef __bf16 bf16_t;
typedef _Float16 hf16_t;
typedef bf16_t bf16x8 __attribute__((ext_vector_type(8)));
typedef bf16_t bf16x4 __attribute__((ext_vector_type(4)));
typedef hf16_t hf16x8 __attribute__((ext_vector_type(8)));
typedef float f32x4 __attribute__((ext_vector_type(4)));
typedef short s16x4 __attribute__((ext_vector_type(4)));

#define B_  4
#define TA_ 1024
#define TV_ 1024
#define D_  512
#define H_  8
#define HD_ 64
#define SCALE_ 0.125f
#define LOG2E_ 1.442695041f
// SCALE * log2(e): folded into Q so attn logits are in log2 units.
#define QSCALE_ 0.1803368801f
// defer-max threshold: 8 nats in log2 units
#define DEFER_THR_ 11.5416f

// hardware exp2 (v_exp_f32). __exp2f is taken by a glibc math.h macro.
__device__ inline float fast_exp2(float x) { return __builtin_amdgcn_exp2f(x); }

// async global->LDS copy, 16 B per lane (global_load_lds_dwordx4).
__device__ inline void g2l16(const void* g, void* l) {
    __builtin_amdgcn_global_load_lds(
        (const __attribute__((address_space(1))) void*)g,
        (__attribute__((address_space(3))) void*)l, 16, 0, 0);
}

__device__ inline f32x4 mfma16_bf16(bf16x4 a, bf16x4 b, f32x4 c) {
    return __builtin_amdgcn_mfma_f32_16x16x16bf16_1k(
        __builtin_bit_cast(s16x4, a), __builtin_bit_cast(s16x4, b), c, 0, 0, 0);
}

// ---- prep: fp32->bf16 cvt only (q,k,v then Wq,Wk,Wv,Wo). 3584 blocks.
__global__ __launch_bounds__(256) void prep_all(
    const float* __restrict__ q, const float* __restrict__ k, const float* __restrict__ v,
    const float* __restrict__ Wq, const float* __restrict__ Wk,
    const float* __restrict__ Wv, const float* __restrict__ Wo,
    bf16_t* __restrict__ qb, bf16_t* __restrict__ kb, bf16_t* __restrict__ vb,
    bf16_t* __restrict__ Wb)
{
    const int tid = threadIdx.x;
    const size_t i = ((size_t)blockIdx.x * 256 + tid) * 8;
    const float* src; bf16_t* dst; size_t off;
    const size_t M2 = (size_t)1 << 21;
    if (i < M2)          { src = q; dst = qb; off = i; }
    else if (i < 2 * M2) { src = k; dst = kb; off = i - M2; }
    else if (i < 3 * M2) { src = v; dst = vb; off = i - 2 * M2; }
    else {
        size_t j = i - 3 * M2;
        int wsel = (int)(j >> 18); off = j & 262143;
        src = (wsel == 0) ? Wq : (wsel == 1) ? Wk : (wsel == 2) ? Wv : Wo;
        dst = Wb + ((size_t)wsel << 18);
    }
    f32x4 a = *(const f32x4*)(src + off), c = *(const f32x4*)(src + off + 4);
    bf16x8 r;
    #pragma unroll
    for (int t = 0; t < 4; ++t) { r[t] = (bf16_t)a[t]; r[t + 4] = (bf16_t)c[t]; }
    *(bf16x8*)(dst + off) = r;
}

// Fused QKV projection + bias tiling in ONE launch (no mutual dependency).
// Blocks [0,768): 128x64 GEMM tiles (z = bx>>8: 0 qb->Qp pre-scaled, 1 kb->Kp,
// 2 vb->Vt). Blocks [768,1792): bias tiling of G -> bias_t (fp16, S^T frag
// order), overlapping the GEMM phase. Shared mem: 24KB union.
__global__ __launch_bounds__(256) void gemm_qkv(
    const bf16_t* __restrict__ qb, const bf16_t* __restrict__ kb, const bf16_t* __restrict__ vb,
    const bf16_t* __restrict__ Wb,
    const float* __restrict__ bq, const float* __restrict__ bk, const float* __restrict__ bv,
    bf16_t* __restrict__ Qp, bf16_t* __restrict__ Kp, bf16_t* __restrict__ Vt,
    const float* __restrict__ G, hf16_t* __restrict__ bias_t)
{
    __shared__ __align__(16) char smem[24576];
    const int tid  = threadIdx.x;

    if (blockIdx.x >= 768) {
        // ---- bias tiling: bias_t[b][kt][q64][tid][ct*4+r] =
        //      log(G[b][q64*64+w*16+l16][kt*64+ct*16+quad*4+r]+1e-8)
        float (*Gt)[68] = (float(*)[68])smem;     // 64x68 fp32 = 17.4 KB
        const int bx = blockIdx.x - 768;
        const int kt = bx & 15, q64 = (bx >> 4) & 15, b = bx >> 8;
        const int row = tid >> 4, col4 = (tid & 15) * 4;
        #pragma unroll
        for (int it = 0; it < 4; ++it) {
            int r = it * 16 + row;
            f32x4 g = *(const f32x4*)(G + ((size_t)(b * TA_ + q64 * 64 + r)) * TV_ + kt * 64 + col4);
            *(f32x4*)&Gt[r][col4] = g;
        }
        __syncthreads();
        const int lane = tid & 63, wave = tid >> 6, quad = lane >> 4, l16 = lane & 15;
        hf16x8 lo, hi;
        #pragma unroll
        for (int ct = 0; ct < 4; ++ct) {
            #pragma unroll
            for (int r = 0; r < 4; ++r) {
                float gv = Gt[wave * 16 + l16][ct * 16 + quad * 4 + r];
                float lb = __logf(gv + 1e-8f);
                int idx = ct * 4 + r;
                if (idx < 8) lo[idx] = (hf16_t)lb; else hi[idx - 8] = (hf16_t)lb;
            }
        }
        size_t doff = ((((size_t)b * 16 + kt) * 16 + q64) * 256 + tid) * 16;
        *(hf16x8*)(bias_t + doff) = lo;
        *(hf16x8*)(bias_t + doff + 8) = hi;
        return;
    }

    // ---- qkv GEMM: decode (z, nbase, mbase) from flat index
    bf16_t (*Asm)[128 * 32] = (bf16_t(*)[128 * 32])smem;            // 16 KB
    bf16_t (*Bsm)[64 * 32]  = (bf16_t(*)[64 * 32])(smem + 16384);   // 8 KB

    const int wave = tid >> 6, lane = tid & 63;
    const int quad = lane >> 4, l16 = lane & 15;
    const int wm = wave & 1, wn = wave >> 1;      // wm: 2x64 rows, wn: 2x32 cols
    const int bx = blockIdx.x;
    const int z = bx >> 8, rem = bx & 255;
    const int mbase = (rem & 31) * 128, nbase = (rem >> 5) * 64;
    const int srow = lane >> 2;           // staging: 16 rows x 4 chunks of 16B
    const int scol = (lane & 3) * 8;      // elements

    const bf16_t* X   = (z == 0) ? qb : (z == 1) ? kb : vb;
    const float* bias = (z == 0) ? bq : (z == 1) ? bk : bv;
    const bf16_t* W   = Wb + ((size_t)z << 18);

    auto stage = [&](int kt, int buf) {
        const int k0 = kt * 32;
        #pragma unroll
        for (int i = 0; i < 2; ++i) {          // A rows: wave*32 .. +32
            const int row = wave * 32 + i * 16;
            g2l16(X + (size_t)(mbase + row + srow) * D_ + k0 + scol,
                  &Asm[buf][row * 32] + (size_t)lane * 8);
        }
        {                                       // B rows: wave*16 .. +16
            const int row = wave * 16;
            g2l16(W + (size_t)(nbase + row + srow) * D_ + k0 + scol,
                  &Bsm[buf][row * 32] + (size_t)lane * 8);
        }
    };

    f32x4 acc[4][2] = {};
    stage(0, 0);
    __syncthreads();
    for (int kt = 0; kt < 16; ++kt) {
        const int buf = kt & 1;
        if (kt < 15) stage(kt + 1, buf ^ 1);
        bf16x8 af[4], bf_[2];
        #pragma unroll
        for (int t = 0; t < 4; ++t)
            af[t]  = *(const bf16x8*)&Asm[buf][(wm * 64 + t * 16 + l16) * 32 + quad * 8];
        #pragma unroll
        for (int t = 0; t < 2; ++t)
            bf_[t] = *(const bf16x8*)&Bsm[buf][(wn * 32 + t * 16 + l16) * 32 + quad * 8];
        #pragma unroll
        for (int mt = 0; mt < 4; ++mt) {
            #pragma unroll
            for (int nt = 0; nt < 2; ++nt)
                acc[mt][nt] = __builtin_amdgcn_mfma_f32_16x16x32_bf16(af[mt], bf_[nt], acc[mt][nt], 0, 0, 0);
        }
        __syncthreads();
    }

    bf16_t* out = (z == 0) ? Qp : (z == 1) ? Kp : Vt;
    #pragma unroll
    for (int mt = 0; mt < 4; ++mt) {
        #pragma unroll
        for (int nt = 0; nt < 2; ++nt) {
            const int n = nbase + wn * 32 + nt * 16 + l16;
            const float bn = bias[n];
            if (z == 2) {
                // 4 consecutive t for r=0..3 -> one aligned 8B store
                int m0 = mbase + wm * 64 + mt * 16 + quad * 4;
                int b = m0 >> 10, t = m0 & 1023, h = n >> 6, hd = n & 63;
                bf16x4 pk;
                #pragma unroll
                for (int r = 0; r < 4; ++r) pk[r] = (bf16_t)(acc[mt][nt][r] + bn);
                *(bf16x4*)(out + ((size_t)(b * H_ + h) * HD_ + hd) * TV_ + t) = pk;
            } else {
                #pragma unroll
                for (int r = 0; r < 4; ++r) {
                    int m = mbase + wm * 64 + mt * 16 + quad * 4 + r;  // token index
                    float val = acc[mt][nt][r] + bn;
                    if (z == 0) val *= QSCALE_;
                    int b = m >> 10, t = m & 1023, h = n >> 6, hd = n & 63;
                    out[(((size_t)(b * H_ + h) * TA_) + t) * HD_ + hd] = (bf16_t)val;
                }
            }
        }
    }
}

// ---- Flash attention, in-block split-K, S^T formulation. 512 threads.
// Waves 0-3: k-tiles 0-7; waves 4-7: k-tiles 8-15 (independent K/V LDS halves).
// S^T frag: q=l16, k=16ct+4quad+r -> per-lane softmax + register P -> 16x16x16 PV.
// Ksm: 16B-granule XOR swizzle (g ^= row&7) on write + both reads.
// Vsm: stride 76 (bank stride 6 mod 32 -> conflict-free-ish); 2x bf16x4 writes.
// Final: half-1 dumps fp32 O/m/l into dead Ksm space; half-0 merges, writes ctx.
__global__ __launch_bounds__(512, 4) void attn_kernel(
    const bf16_t* __restrict__ Qp, const bf16_t* __restrict__ Kp,
    const bf16_t* __restrict__ Vt, const hf16_t* __restrict__ bias_t,
    const float* __restrict__ bias_scale, bf16_t* __restrict__ ctx)
{
    __shared__ bf16_t Ksm[2][2][64][72];   // [half][buf][krow][hd], XOR-swizzled
    __shared__ bf16_t Vsm[2][2][64][76];   // [half][buf][hd][kcol], stride 76

    const int tid  = threadIdx.x;
    const int wave = tid >> 6, lane = tid & 63;
    const int half = wave >> 2, w4 = wave & 3;
    const int quad = lane >> 4, l16 = lane & 15;
    const int bh = blockIdx.x, b = bh >> 3, h = bh & 7;
    const int q64 = blockIdx.y;
    const int t0 = half * 8;            // first k-tile for this half
    const int qbase = q64 * 64 + w4 * 16;
    const int rsub = lane >> 3, csub = lane & 7;   // staging: 8 rows x 8 chunks of 16B
    // shuffle source lane: same quad, l16' = quad*4+r  (|r at use site)
    const int shsrc = (lane & 48) | ((lane >> 2) & 12);

    // softplus(bias_scale) * log2e (logits kept in log2 units)
    const float sp = log1pf(__expf(bias_scale[0])) * LOG2E_;

    // Q fragments (MFMA B operand: n=l16=q, k=hd)
    bf16x8 aq[2];
    #pragma unroll
    for (int s = 0; s < 2; ++s)
        aq[s] = *(const bf16x8*)(Qp + ((size_t)bh * TA_ + qbase + l16) * HD_ + s * 32 + quad * 8);

    f32x4 o[4] = {};
    float m_ = -1e30f, l_ = 0.f;   // per-lane: q-row l16 (log2 units)

    auto issue_kv = [&](int kt, bf16x8 kr[2], bf16x8 vr[2]) {
        const int kbase = kt * 64;
        #pragma unroll
        for (int i = 0; i < 2; ++i) {
            int row = w4 * 16 + i * 8 + rsub;
            kr[i] = *(const bf16x8*)(Kp + ((size_t)bh * TV_ + kbase + row) * HD_ + csub * 8);
            vr[i] = *(const bf16x8*)(Vt + ((size_t)bh * HD_ + row) * TV_ + kbase + csub * 8);
        }
    };
    auto write_kv = [&](int buf, bf16x8 kr[2], bf16x8 vr[2]) {
        #pragma unroll
        for (int i = 0; i < 2; ++i) {
            int row = w4 * 16 + i * 8 + rsub;
            // K: swizzled 16B granule (write side of the involution)
            *(bf16x8*)&Ksm[half][buf][row][(csub ^ (row & 7)) * 8] = kr[i];
            // V: stride-76 rows; odd rows only 8B-aligned -> two bf16x4 stores
            *(bf16x4*)&Vsm[half][buf][row][csub * 8]     = *(const bf16x4*)&vr[i];
            *(bf16x4*)&Vsm[half][buf][row][csub * 8 + 4] = *((const bf16x4*)&vr[i] + 1);
        }
    };

    const int tidb = (w4 << 6) | lane;   // 0..255 packet index within (b,kt,q64)
    const hf16_t* bias_base = bias_t + (((size_t)b * 16 * 16 + q64) * 256 + tidb) * 16;
    auto bias_ld = [&](int kt, hf16x8& lo, hf16x8& hi) {
        const hf16_t* bp = bias_base + (size_t)kt * 65536;  // kt stride = 16*256*16
        lo = *(const hf16x8*)bp;
        hi = *(const hf16x8*)(bp + 8);
    };
    // static ring slots: slot0 = even local tiles, slot1 = odd
    hf16x8 b0lo, b0hi, b1lo, b1hi;
    bias_ld(t0, b0lo, b0hi);
    bias_ld(t0 + 1, b1lo, b1hi);

    {
        bf16x8 kr[2], vr[2];
        issue_kv(t0, kr, vr);
        write_kv(0, kr, vr);
    }
    __syncthreads();

    // one K-tile; lk = local tile index (0..7), buf literal, static ring slot refs
    auto tile_body = [&](int lk, int buf, hf16x8& slo, hf16x8& shi) {
        const int kt = t0 + lk;
        bf16x8 krn[2], vrn[2];
        if (lk < 7) issue_kv(kt + 1, krn, vrn);
        hf16x8 clo = slo, chi = shi;
        if (lk < 6) bias_ld(kt + 2, slo, shi);

        // S^T = K . Q^T  (A = K frag from Ksm swizzled, B = Q frag; Q pre-scaled)
        f32x4 st[4];
        __builtin_amdgcn_s_setprio(1);
        #pragma unroll
        for (int ct = 0; ct < 4; ++ct) {
            f32x4 acc = {};
            #pragma unroll
            for (int s = 0; s < 2; ++s) {
                bf16x8 bk = *(const bf16x8*)&Ksm[half][buf][ct * 16 + l16]
                                                 [((4 * s + quad) ^ (l16 & 7)) * 8];
                acc = __builtin_amdgcn_mfma_f32_16x16x32_bf16(bk, aq[s], acc, 0, 0, 0);
            }
            st[ct] = acc;
        }
        __builtin_amdgcn_s_setprio(0);
        // bias + per-lane softmax over 16 regs (k = 16ct+4quad+r for q = l16)
        float sv[4][4], mx = -1e30f;
        #pragma unroll
        for (int ct = 0; ct < 4; ++ct) {
            #pragma unroll
            for (int r = 0; r < 4; ++r) {
                int idx = ct * 4 + r;
                float lb = (idx < 8) ? (float)clo[idx] : (float)chi[idx - 8];
                float val = fmaf(lb, sp, st[ct][r]);
                sv[ct][r] = val;
                mx = fmaxf(mx, val);
            }
        }
        mx = fmaxf(mx, __shfl_xor(mx, 16, 64));
        mx = fmaxf(mx, __shfl_xor(mx, 32, 64));
        // defer-max (T13): skip O-rescale when tile max growth <= 8 nats.
        // Wave-uniform branch; exact when mx <= m_.
        float mn;
        if (__all(mx - m_ <= DEFER_THR_)) {
            mn = m_;
        } else {
            mn = fmaxf(m_, mx);
            float alpha = fast_exp2(m_ - mn);
            m_ = mn;
            l_ *= alpha;
            // redistribute alpha to O's C-frag rows (q = quad*4+r), rescale O
            #pragma unroll
            for (int r = 0; r < 4; ++r) {
                float af = __shfl(alpha, shsrc | r, 64);
                #pragma unroll
                for (int dt = 0; dt < 4; ++dt) o[dt][r] *= af;
            }
        }
        float ls = 0.f;
        #pragma unroll
        for (int ct = 0; ct < 4; ++ct) {
            #pragma unroll
            for (int r = 0; r < 4; ++r) {
                float p = fast_exp2(sv[ct][r] - mn);
                sv[ct][r] = p;
                ls += p;
            }
        }
        ls += __shfl_xor(ls, 16, 64);
        ls += __shfl_xor(ls, 32, 64);
        l_ += ls;
        // stage next tile into buf^1 now: ds_writes drain under the PV MFMAs
        if (lk < 7) write_kv(buf ^ 1, krn, vrn);
        // O += P.V via 16x16x16 MFMA: A = P chunk (regs), B = V chunk (b64 from Vsm)
        __builtin_amdgcn_s_setprio(1);
        #pragma unroll
        for (int ct = 0; ct < 4; ++ct) {
            bf16x4 ap;
            #pragma unroll
            for (int r = 0; r < 4; ++r) ap[r] = (bf16_t)sv[ct][r];
            #pragma unroll
            for (int dt = 0; dt < 4; ++dt) {
                bf16x4 bv = *(const bf16x4*)&Vsm[half][buf][dt * 16 + l16][ct * 16 + quad * 4];
                o[dt] = mfma16_bf16(ap, bv, o[dt]);
            }
        }
        __builtin_amdgcn_s_setprio(0);
        __syncthreads();
    };

    #pragma unroll 1
    for (int kk = 0; kk < 8; kk += 2) {
        tile_body(kk,     0, b0lo, b0hi);
        tile_body(kk + 1, 1, b1lo, b1hi);
    }

    // ---- in-block combine: Ksm is dead; reuse as fp32 buffer [256][18]
    float* cb = (float*)&Ksm[0][0][0][0];
    if (half == 1) {
        float* p = cb + (size_t)tidb * 18;
        #pragma unroll
        for (int dt = 0; dt < 4; ++dt) {
            #pragma unroll
            for (int r = 0; r < 4; ++r) p[dt * 4 + r] = o[dt][r];
        }
        p[16] = m_; p[17] = l_;
    }
    __syncthreads();
    if (half == 0) {
        const float* p = cb + (size_t)tidb * 18;   // half1's same-lane O
        float s0[4], s1[4];
        #pragma unroll
        for (int r = 0; r < 4; ++r) {
            float m0 = __shfl(m_, shsrc | r, 64);
            float l0 = __shfl(l_, shsrc | r, 64);
            const float* pr = cb + (size_t)((w4 << 6) | (shsrc | r)) * 18;
            float m1 = pr[16], l1 = pr[17];
            float mm = fmaxf(m0, m1);
            float e0 = fast_exp2(m0 - mm), e1 = fast_exp2(m1 - mm);
            float L = l0 * e0 + l1 * e1;
            s0[r] = e0 / L; s1[r] = e1 / L;
        }
        #pragma unroll
        for (int dt = 0; dt < 4; ++dt) {
            #pragma unroll
            for (int r = 0; r < 4; ++r) {
                float v = o[dt][r] * s0[r] + p[dt * 4 + r] * s1[r];
                int qrow = q64 * 64 + w4 * 16 + quad * 4 + r;
                ctx[((size_t)b * TA_ + qrow) * D_ + h * HD_ + dt * 16 + l16] = (bf16_t)v;
            }
        }
    }
}

// ---- Fused out-projection + gated residual + LayerNorm.
// Block: 16 tokens x full 512 cols, 512 threads, grid 256 (1 block/CU).
// Each wave owns 64 cols (4x nt) for all 16 tokens. LN row stats: shfl_xor
// over l16 lanes, then [16][8] LDS combine across the 8 waves.
__global__ __launch_bounds__(512) void gemm_out_ln(
    const bf16_t* __restrict__ ctx, const bf16_t* __restrict__ Wob,
    const float* __restrict__ bo, const float* __restrict__ q,
    const float* __restrict__ gamma, const float* __restrict__ beta,
    const float* __restrict__ gate, float* __restrict__ y)
{
    __shared__ bf16_t Asm[2][16 * 32];    // 1 KB per buf
    __shared__ bf16_t Bsm[2][512 * 32];   // 32 KB per buf
    __shared__ float ps[16][8], psq[16][8];

    const int tid  = threadIdx.x;
    const int wave = tid >> 6, lane = tid & 63;
    const int quad = lane >> 4, l16 = lane & 15;
    const int mbase = blockIdx.x * 16;

    auto stage = [&](int kt, int buf) {
        const int k0 = kt * 32;
        #pragma unroll
        for (int j = 0; j < 4; ++j) {
            int row0 = wave * 64 + j * 16;   // B rows [row0, row0+16)
            g2l16(Wob + (size_t)(row0 + (lane >> 2)) * D_ + k0 + (lane & 3) * 8,
                  &Bsm[buf][row0 * 32] + (size_t)lane * 8);
        }
        if (wave == 0) {                     // A rows [0,16)
            g2l16(ctx + (size_t)(mbase + (lane >> 2)) * D_ + k0 + (lane & 3) * 8,
                  &Asm[buf][0] + (size_t)lane * 8);
        }
    };

    f32x4 acc[4] = {};
    stage(0, 0);
    __syncthreads();
    for (int kt = 0; kt < 16; ++kt) {
        const int buf = kt & 1;
        if (kt < 15) stage(kt + 1, buf ^ 1);
        bf16x8 af = *(const bf16x8*)&Asm[buf][l16 * 32 + quad * 8];
        #pragma unroll
        for (int nt = 0; nt < 4; ++nt) {
            bf16x8 bf_ = *(const bf16x8*)&Bsm[buf][(wave * 64 + nt * 16 + l16) * 32 + quad * 8];
            acc[nt] = __builtin_amdgcn_mfma_f32_16x16x32_bf16(af, bf_, acc[nt], 0, 0, 0);
        }
        __syncthreads();
    }

    const float sg = 1.f / (1.f + __expf(-gate[0]));
    // x = q + sg*(acc + bo); keep x in acc; accumulate row partials (64 cols/wave)
    float s[4] = {0.f, 0.f, 0.f, 0.f}, sq[4] = {0.f, 0.f, 0.f, 0.f};
    #pragma unroll
    for (int nt = 0; nt < 4; ++nt) {
        int n = wave * 64 + nt * 16 + l16;
        float bon = bo[n];
        #pragma unroll
        for (int r = 0; r < 4; ++r) {
            int m = mbase + quad * 4 + r;
            float x = q[(size_t)m * D_ + n] + sg * (acc[nt][r] + bon);
            acc[nt][r] = x;
            s[r] += x; sq[r] += x * x;
        }
    }
    // reduce over the 16 l16-lanes (offsets stay inside the quad-group)
    #pragma unroll
    for (int off = 1; off < 16; off <<= 1) {
        #pragma unroll
        for (int r = 0; r < 4; ++r) {
            s[r]  += __shfl_xor(s[r],  off, 64);
            sq[r] += __shfl_xor(sq[r], off, 64);
        }
    }
    if (l16 == 0) {
        #pragma unroll
        for (int r = 0; r < 4; ++r) {
            ps[quad * 4 + r][wave]  = s[r];
            psq[quad * 4 + r][wave] = sq[r];
        }
    }
    __syncthreads();
    float mu[4], rstd[4];
    #pragma unroll
    for (int r = 0; r < 4; ++r) {
        int row = quad * 4 + r;
        float S = 0.f, SQ = 0.f;
        #pragma unroll
        for (int wv = 0; wv < 8; ++wv) { S += ps[row][wv]; SQ += psq[row][wv]; }
        mu[r] = S * (1.f / D_);
        float var = SQ * (1.f / D_) - mu[r] * mu[r];
        rstd[r] = rsqrtf(var + 1e-5f);
    }
    #pragma unroll
    for (int nt = 0; nt < 4; ++nt) {
        int n = wave * 64 + nt * 16 + l16;
        float gn = gamma[n], bn = beta[n];
        #pragma unroll
        for (int r = 0; r < 4; ++r) {
            int m = mbase + quad * 4 + r;
            y[(size_t)m * D_ + n] = (acc[nt][r] - mu[r]) * rstd[r] * gn + bn;
        }
    }
}

extern "C" void kernel_launch(void* const* d_in, const int* in_sizes, int n_in,
                              void* d_out, int out_size, void* d_ws, size_t ws_size,
                              hipStream_t stream) {
    const float* q       = (const float*)d_in[0];
    const float* k       = (const float*)d_in[1];
    const float* v       = (const float*)d_in[2];
    const float* guide   = (const float*)d_in[3];
    const float* Wq      = (const float*)d_in[4];
    const float* bq      = (const float*)d_in[5];
    const float* Wk      = (const float*)d_in[6];
    const float* bk      = (const float*)d_in[7];
    const float* Wv      = (const float*)d_in[8];
    const float* bv      = (const float*)d_in[9];
    const float* Wo      = (const float*)d_in[10];
    const float* bo      = (const float*)d_in[11];
    const float* gamma   = (const float*)d_in[12];
    const float* beta    = (const float*)d_in[13];
    const float* gate    = (const float*)d_in[14];
    const float* bscale  = (const float*)d_in[15];

    char* w = (char*)d_ws;
    bf16_t* qb     = (bf16_t*)(w);                  // 4 MB bf16 [4096,512]
    bf16_t* kb     = (bf16_t*)(w + (4u  << 20));    // 4 MB
    bf16_t* vb     = (bf16_t*)(w + (8u  << 20));    // 4 MB
    bf16_t* Wb     = (bf16_t*)(w + (12u << 20));    // 2 MB concat Wq,Wk,Wv,Wo bf16
    bf16_t* Qp     = (bf16_t*)(w + (14u << 20));    // 4 MB [B,H,TA,HD] (pre-scaled)
    bf16_t* Kp     = (bf16_t*)(w + (18u << 20));    // 4 MB [B,H,TV,HD]
    bf16_t* Vt     = (bf16_t*)(w + (22u << 20));    // 4 MB [B,H,HD,TV]
    bf16_t* ctx    = (bf16_t*)(w + (26u << 20));    // 4 MB [B,TA,D]
    hf16_t* bias_t = (hf16_t*)(w + (30u << 20));    // 8 MB tiled fp16

    prep_all<<<3584, 256, 0, stream>>>(q, k, v, Wq, Wk, Wv, Wo, qb, kb, vb, Wb);
    gemm_qkv<<<1792, 256, 0, stream>>>(qb, kb, vb, Wb, bq, bk, bv, Qp, Kp, Vt,
                                       guide, bias_t);
    attn_kernel<<<dim3(32, 16), 512, 0, stream>>>(Qp, Kp, Vt, bias_t, bscale, ctx);
    gemm_out_ln<<<256, 512, 0, stream>>>(ctx, Wb + ((size_t)3 << 18), bo, q,
                                         gamma, beta, gate, (float*)d_out);
}